// Round 3
// baseline (304.716 us; speedup 1.0000x reference)
//
#include <hip/hip_runtime.h>
#include <math.h>

// Problem: x[128, 1, 512, 512] fp32.
//   pred = softplus(x); m = max(pred) per sample; out = m > 1e-8 ? pred/m : pred
// softplus is strictly monotone -> per-sample max of pred == softplus(raw max).
//
// R8: fused single-dispatch, join FIXED vs R6's 10%-BW collapse:
//  - R6 polled with ACQUIRE agent-scope loads (per-poll cache invalidate) and
//    published with a RELEASE fetch_add (per-block L2 flush) -> machine-wide
//    serialization. R8 uses RELAXED atomics only; key-before-counter order is
//    enforced physically by keeping atomicMax's return value live (forces
//    s_waitcnt vmcnt(0) before the counter increment issues).
//  - R6's __launch_bounds__(256,4) left half the grid non-resident. R8 lets
//    all 2048 blocks co-reside (8 blocks/CU at ~56 VGPR) -> join skew ~= 0.
//  - Phase 3 re-reads the block's own chunk TAIL-FIRST: the tail was read
//    last in phase 1 and no kernel boundary/acquire invalidated L1/L2, so the
//    leading re-reads hit cache; one dispatch also removes the inter-kernel
//    L2 flush + second launch that the two-pass structure pays.
// Safety: bounded spin + block-local full-sample rescan fallback (correct,
// slow, never deadlocks) if peers are somehow never co-scheduled.

#define PER_SAMPLE (512 * 512)                       // 262144 floats / sample
#define F4_PER_SAMPLE (PER_SAMPLE / 4)               // 65536 float4
#define BLOCKS_PER_SAMPLE 16
#define THREADS 256
#define F4_PER_BLOCK (F4_PER_SAMPLE / BLOCKS_PER_SAMPLE) // 4096 float4
#define F4_PER_THREAD (F4_PER_BLOCK / THREADS)           // 16 float4 / thread
#define BATCH 4                                          // loads in flight
#define NBATCH (F4_PER_THREAD / BATCH)                   // 4

typedef float f32x4 __attribute__((ext_vector_type(4)));

__device__ __forceinline__ float softplus_f(float x) {
    // max(x,0) + log1p(exp(-|x|)); abs err ~6e-8 << 2e-2 threshold.
    return fmaxf(x, 0.0f) + __logf(1.0f + __expf(-fabsf(x)));
}

// Monotone float -> uint mapping so unsigned atomicMax orders like float.
__device__ __forceinline__ unsigned key_of(float f) {
    unsigned u = __float_as_uint(f);
    return (u & 0x80000000u) ? ~u : (u | 0x80000000u);
}
__device__ __forceinline__ float float_of_key(unsigned k) {
    unsigned u = (k & 0x80000000u) ? (k ^ 0x80000000u) : ~k;
    return __uint_as_float(u);
}

__global__ __launch_bounds__(THREADS) void fused_kernel(
        const float* __restrict__ x, unsigned* __restrict__ ws,
        float* __restrict__ out, int n_samples) {
    const int sample = blockIdx.x / BLOCKS_PER_SAMPLE;
    const int part   = blockIdx.x % BLOCKS_PER_SAMPLE;
    const int t      = threadIdx.x;

    const size_t base =
        (size_t)sample * F4_PER_SAMPLE + (size_t)part * F4_PER_BLOCK;
    const f32x4* x4 = (const f32x4*)x + base;
    f32x4* o4       = (f32x4*)out + base;

    // ---- phase 1: block max of raw x over this 64 KB chunk ----
    float m = -INFINITY;
#pragma unroll
    for (int b = 0; b < NBATCH; ++b) {
        f32x4 v[BATCH];
#pragma unroll
        for (int j = 0; j < BATCH; ++j)              // 4 loads back-to-back
            v[j] = x4[(size_t)(b * BATCH + j) * THREADS + t];
#pragma unroll
        for (int j = 0; j < BATCH; ++j)
            m = fmaxf(m, fmaxf(fmaxf(v[j].x, v[j].y), fmaxf(v[j].z, v[j].w)));
    }
#pragma unroll
    for (int off = 32; off > 0; off >>= 1)
        m = fmaxf(m, __shfl_down(m, off, 64));

    __shared__ float wmax[THREADS / 64];
    __shared__ float s_scale;
    __shared__ int   s_ok;
    if ((t & 63) == 0) wmax[t >> 6] = m;
    __syncthreads();

    // ---- phase 2: relaxed publish + relaxed poll (no invalidates/flushes) --
    if (t == 0) {
        float bm = wmax[0];
#pragma unroll
        for (int w = 1; w < THREADS / 64; ++w) bm = fmaxf(bm, wmax[w]);

        unsigned* keys = ws;
        unsigned* cnts = ws + n_samples;

        unsigned old = atomicMax(&keys[sample], key_of(bm)); // device scope
        asm volatile("" :: "v"(old));   // keep result live -> vmcnt(0) wait
                                        // -> max complete BEFORE cnt bump
        unsigned tick = __hip_atomic_fetch_add(
            &cnts[sample], 1u, __ATOMIC_RELAXED, __HIP_MEMORY_SCOPE_AGENT);
        asm volatile("" :: "v"(tick));

        int ok = 1, spins = 0;
        while (__hip_atomic_load(&cnts[sample], __ATOMIC_RELAXED,
                                 __HIP_MEMORY_SCOPE_AGENT)
               < (unsigned)BLOCKS_PER_SAMPLE) {
            __builtin_amdgcn_s_sleep(8);                 // ~512 cyc backoff
            if (++spins > 100000) { ok = 0; break; }     // ~20 ms valve
        }
        s_ok = ok;
        float raw = float_of_key(__hip_atomic_load(
            &keys[sample], __ATOMIC_RELAXED, __HIP_MEMORY_SCOPE_AGENT));
        float mm  = softplus_f(raw);                     // > 0 always
        s_scale   = (mm > 1e-8f) ? (1.0f / mm) : 1.0f;
    }
    __syncthreads();

    float scale = s_scale;
    if (!s_ok) {
        // Pathological fallback: block-wide rescan of the whole sample.
        const f32x4* s4 = (const f32x4*)x + (size_t)sample * F4_PER_SAMPLE;
        float fm = -INFINITY;
        for (int i = t; i < F4_PER_SAMPLE; i += THREADS) {
            f32x4 w = s4[i];
            fm = fmaxf(fm, fmaxf(fmaxf(w.x, w.y), fmaxf(w.z, w.w)));
        }
#pragma unroll
        for (int off = 32; off > 0; off >>= 1)
            fm = fmaxf(fm, __shfl_down(fm, off, 64));
        __shared__ float fwmax[THREADS / 64];
        if ((t & 63) == 0) fwmax[t >> 6] = fm;
        __syncthreads();
        float raw = fmaxf(fmaxf(fwmax[0], fwmax[1]), fmaxf(fwmax[2], fwmax[3]));
        float mm  = softplus_f(raw);
        scale     = (mm > 1e-8f) ? (1.0f / mm) : 1.0f;
    }

    // ---- phase 3: re-read own chunk TAIL-FIRST (L1/L2-warm), scale, store --
#pragma unroll
    for (int b = NBATCH - 1; b >= 0; --b) {
        f32x4 v[BATCH];
#pragma unroll
        for (int j = 0; j < BATCH; ++j)
            v[j] = x4[(size_t)(b * BATCH + j) * THREADS + t];
#pragma unroll
        for (int j = 0; j < BATCH; ++j) {
            f32x4 r;
            r.x = softplus_f(v[j].x) * scale;
            r.y = softplus_f(v[j].y) * scale;
            r.z = softplus_f(v[j].z) * scale;
            r.w = softplus_f(v[j].w) * scale;
            o4[(size_t)(b * BATCH + j) * THREADS + t] = r;
        }
    }
}

extern "C" void kernel_launch(void* const* d_in, const int* in_sizes, int n_in,
                              void* d_out, int out_size, void* d_ws, size_t ws_size,
                              hipStream_t stream) {
    const float* x = (const float*)d_in[0];
    float* out     = (float*)d_out;
    unsigned* ws   = (unsigned*)d_ws;

    const int n_total   = in_sizes[0];
    const int n_samples = n_total / PER_SAMPLE;              // 128
    const int grid      = n_samples * BLOCKS_PER_SAMPLE;     // 2048 blocks

    // ws[0..n) = max keys, ws[n..2n) = arrival counters; poisoned each iter.
    hipMemsetAsync(ws, 0, 2 * n_samples * sizeof(unsigned), stream);
    fused_kernel<<<grid, THREADS, 0, stream>>>(x, ws, out, n_samples);
}

// Round 4
// 256.702 us; speedup vs baseline: 1.1870x; 1.1870x over previous
//
#include <hip/hip_runtime.h>
#include <math.h>

// Problem: x[128, 1, 512, 512] fp32.
//   pred = softplus(x); m = max(pred) per sample; out = m > 1e-8 ? pred/m : pred
// softplus is strictly monotone -> per-sample max of pred == softplus(raw max).
//
// R9: fused single-dispatch with GUARANTEED co-residency.
//  - R8 (2048 blocks = exactly full wave capacity) convoyed at the join:
//    64% occupancy, 19% BW -> some sample-peers were not resident while
//    their peers spun. R9 launches 1024 blocks (4096 waves = HALF capacity,
//    8 blocks/sample x 128 KB chunks) so every block is resident from t=0;
//    the per-sample join completes as soon as the read flood drains.
//  - Join kept from R8 (it passed + halved FETCH): relaxed device-scope
//    atomics only; atomicMax's result is kept live (asm) so vmcnt(0) orders
//    the max before the counter bump; pollers use relaxed loads + s_sleep.
//  - Phase 3 re-reads the block's own chunk tail-first (L2/L3-warm: R8
//    measured FETCH 115 MB for 268 MB of logical reads).
// Safety: bounded spin + block-local full-sample rescan fallback (correct,
// slow, never deadlocks) if peers are somehow never co-scheduled.

#define PER_SAMPLE (512 * 512)                       // 262144 floats / sample
#define F4_PER_SAMPLE (PER_SAMPLE / 4)               // 65536 float4
#define BLOCKS_PER_SAMPLE 8
#define THREADS 256
#define F4_PER_BLOCK (F4_PER_SAMPLE / BLOCKS_PER_SAMPLE) // 8192 float4
#define F4_PER_THREAD (F4_PER_BLOCK / THREADS)           // 32 float4 / thread
#define BATCH 4                                          // loads in flight
#define NBATCH (F4_PER_THREAD / BATCH)                   // 8

typedef float f32x4 __attribute__((ext_vector_type(4)));

__device__ __forceinline__ float softplus_f(float x) {
    // max(x,0) + log1p(exp(-|x|)); abs err ~6e-8 << 2e-2 threshold.
    return fmaxf(x, 0.0f) + __logf(1.0f + __expf(-fabsf(x)));
}

// Monotone float -> uint mapping so unsigned atomicMax orders like float.
__device__ __forceinline__ unsigned key_of(float f) {
    unsigned u = __float_as_uint(f);
    return (u & 0x80000000u) ? ~u : (u | 0x80000000u);
}
__device__ __forceinline__ float float_of_key(unsigned k) {
    unsigned u = (k & 0x80000000u) ? (k ^ 0x80000000u) : ~k;
    return __uint_as_float(u);
}

__global__ __launch_bounds__(THREADS) void fused_kernel(
        const float* __restrict__ x, unsigned* __restrict__ ws,
        float* __restrict__ out, int n_samples) {
    const int sample = blockIdx.x / BLOCKS_PER_SAMPLE;
    const int part   = blockIdx.x % BLOCKS_PER_SAMPLE;
    const int t      = threadIdx.x;

    const size_t base =
        (size_t)sample * F4_PER_SAMPLE + (size_t)part * F4_PER_BLOCK;
    const f32x4* x4 = (const f32x4*)x + base;
    f32x4* o4       = (f32x4*)out + base;

    // ---- phase 1: block max of raw x over this 128 KB chunk ----
    float m = -INFINITY;
#pragma unroll
    for (int b = 0; b < NBATCH; ++b) {
        f32x4 v[BATCH];
#pragma unroll
        for (int j = 0; j < BATCH; ++j)              // 4 loads back-to-back
            v[j] = x4[(size_t)(b * BATCH + j) * THREADS + t];
#pragma unroll
        for (int j = 0; j < BATCH; ++j)
            m = fmaxf(m, fmaxf(fmaxf(v[j].x, v[j].y), fmaxf(v[j].z, v[j].w)));
    }
#pragma unroll
    for (int off = 32; off > 0; off >>= 1)
        m = fmaxf(m, __shfl_down(m, off, 64));

    __shared__ float wmax[THREADS / 64];
    __shared__ float s_scale;
    __shared__ int   s_ok;
    if ((t & 63) == 0) wmax[t >> 6] = m;
    __syncthreads();

    // ---- phase 2: relaxed publish + relaxed poll (no invalidates/flushes) --
    if (t == 0) {
        float bm = wmax[0];
#pragma unroll
        for (int w = 1; w < THREADS / 64; ++w) bm = fmaxf(bm, wmax[w]);

        unsigned* keys = ws;
        unsigned* cnts = ws + n_samples;

        unsigned old = atomicMax(&keys[sample], key_of(bm)); // device scope
        asm volatile("" :: "v"(old));   // keep result live -> vmcnt(0) wait
                                        // -> max complete BEFORE cnt bump
        unsigned tick = __hip_atomic_fetch_add(
            &cnts[sample], 1u, __ATOMIC_RELAXED, __HIP_MEMORY_SCOPE_AGENT);
        asm volatile("" :: "v"(tick));

        int ok = 1, spins = 0;
        while (__hip_atomic_load(&cnts[sample], __ATOMIC_RELAXED,
                                 __HIP_MEMORY_SCOPE_AGENT)
               < (unsigned)BLOCKS_PER_SAMPLE) {
            __builtin_amdgcn_s_sleep(8);                 // ~512 cyc backoff
            if (++spins > 100000) { ok = 0; break; }     // ~20 ms valve
        }
        s_ok = ok;
        float raw = float_of_key(__hip_atomic_load(
            &keys[sample], __ATOMIC_RELAXED, __HIP_MEMORY_SCOPE_AGENT));
        float mm  = softplus_f(raw);                     // > 0 always
        s_scale   = (mm > 1e-8f) ? (1.0f / mm) : 1.0f;
    }
    __syncthreads();

    float scale = s_scale;
    if (!s_ok) {
        // Pathological fallback: block-wide rescan of the whole sample.
        const f32x4* s4 = (const f32x4*)x + (size_t)sample * F4_PER_SAMPLE;
        float fm = -INFINITY;
        for (int i = t; i < F4_PER_SAMPLE; i += THREADS) {
            f32x4 w = s4[i];
            fm = fmaxf(fm, fmaxf(fmaxf(w.x, w.y), fmaxf(w.z, w.w)));
        }
#pragma unroll
        for (int off = 32; off > 0; off >>= 1)
            fm = fmaxf(fm, __shfl_down(fm, off, 64));
        __shared__ float fwmax[THREADS / 64];
        if ((t & 63) == 0) fwmax[t >> 6] = fm;
        __syncthreads();
        float raw = fmaxf(fmaxf(fwmax[0], fwmax[1]), fmaxf(fwmax[2], fwmax[3]));
        float mm  = softplus_f(raw);
        scale     = (mm > 1e-8f) ? (1.0f / mm) : 1.0f;
    }

    // ---- phase 3: re-read own chunk TAIL-FIRST (L2/L3-warm), scale, store --
#pragma unroll
    for (int b = NBATCH - 1; b >= 0; --b) {
        f32x4 v[BATCH];
#pragma unroll
        for (int j = 0; j < BATCH; ++j)
            v[j] = x4[(size_t)(b * BATCH + j) * THREADS + t];
#pragma unroll
        for (int j = 0; j < BATCH; ++j) {
            f32x4 r;
            r.x = softplus_f(v[j].x) * scale;
            r.y = softplus_f(v[j].y) * scale;
            r.z = softplus_f(v[j].z) * scale;
            r.w = softplus_f(v[j].w) * scale;
            o4[(size_t)(b * BATCH + j) * THREADS + t] = r;
        }
    }
}

extern "C" void kernel_launch(void* const* d_in, const int* in_sizes, int n_in,
                              void* d_out, int out_size, void* d_ws, size_t ws_size,
                              hipStream_t stream) {
    const float* x = (const float*)d_in[0];
    float* out     = (float*)d_out;
    unsigned* ws   = (unsigned*)d_ws;

    const int n_total   = in_sizes[0];
    const int n_samples = n_total / PER_SAMPLE;              // 128
    const int grid      = n_samples * BLOCKS_PER_SAMPLE;     // 1024 blocks
                                                             // = 4096 waves
                                                             // = HALF capacity

    // ws[0..n) = max keys, ws[n..2n) = arrival counters; poisoned each iter.
    hipMemsetAsync(ws, 0, 2 * n_samples * sizeof(unsigned), stream);
    fused_kernel<<<grid, THREADS, 0, stream>>>(x, ws, out, n_samples);
}